// Round 2
// baseline (677.425 us; speedup 1.0000x reference)
//
#include <hip/hip_runtime.h>

// Problem constants (from setup_inputs):
//   x: [4096,1] f32, edge_index: [2,131072] delivered as int32, W1: [1,8] f32,
//   b1: [8] f32, Wr: [32768,4096] f32 (512 MB -- the whole cost), br: [4096] f32
//   out: [4096] f32
#define N_NODES 4096
#define HID 8
#define N_EDGES 131072
#define YDIM 4096
#define K_TOT (N_NODES * HID)   // 32768
#define KC 128                  // K-chunk per gemv block
#define GEMV_BLOCK 256

// ---- K1: init deg (self-loop = 1), t accumulator, and out = br ----
__global__ __launch_bounds__(256) void k_init(float* __restrict__ deg,
                                              float* __restrict__ t,
                                              float* __restrict__ out,
                                              const float* __restrict__ br) {
  int i = blockIdx.x * blockDim.x + threadIdx.x;
  if (i < N_NODES) { deg[i] = 1.0f; t[i] = 0.0f; }
  if (i < YDIM) out[i] = br[i];
}

// ---- K2: degree count over dst (edge_index delivered as int32) ----
__global__ __launch_bounds__(256) void k_deg(const int* __restrict__ ei,
                                             float* __restrict__ deg) {
  int e = blockIdx.x * blockDim.x + threadIdx.x;
  if (e < N_EDGES) {
    int d = ei[N_EDGES + e];   // edge_index[1] = dst
    atomicAdd(&deg[d], 1.0f);
  }
}

// ---- K3: dinv = rsqrt(deg)  (deg >= 1 always, self loops) ----
__global__ __launch_bounds__(256) void k_dinv(const float* __restrict__ deg,
                                              float* __restrict__ dinv) {
  int i = blockIdx.x * blockDim.x + threadIdx.x;
  if (i < N_NODES) dinv[i] = rsqrtf(deg[i]);
}

// ---- K4: scalar message scatter: t[dst] += x[src]*dinv[src] ----
__global__ __launch_bounds__(256) void k_scatter(const int* __restrict__ ei,
                                                 const float* __restrict__ x,
                                                 const float* __restrict__ dinv,
                                                 float* __restrict__ t) {
  int e = blockIdx.x * blockDim.x + threadIdx.x;
  if (e < N_EDGES) {
    int s = ei[e];             // edge_index[0] = src
    int d = ei[N_EDGES + e];   // edge_index[1] = dst
    atomicAdd(&t[d], x[s] * dinv[s]);
  }
}

// ---- K5: h[i*8+j] = relu( dinv[i]*(t[i] + x[i]*dinv[i]) * W1[j] + b1[j] ) ----
__global__ __launch_bounds__(256) void k_h(const float* __restrict__ x,
                                           const float* __restrict__ dinv,
                                           const float* __restrict__ t,
                                           const float* __restrict__ W1,
                                           const float* __restrict__ b1,
                                           float* __restrict__ h) {
  int i = blockIdx.x * blockDim.x + threadIdx.x;
  if (i < N_NODES) {
    float di = dinv[i];
    float s = di * (t[i] + x[i] * di);
#pragma unroll
    for (int j = 0; j < HID; ++j) {
      float v = s * W1[j] + b1[j];
      h[i * HID + j] = v > 0.0f ? v : 0.0f;
    }
  }
}

// ---- K6: split-K GEMV  y[j] += sum_k h[k] * Wr[k, j] ----
// grid = 4 column-groups x (K_TOT/KC) chunks. Each block:
//   - compacts nonzero h of its chunk into shared (relu kills ~50% of rows;
//     a skipped row is 16 KB of Wr never fetched from HBM)
//   - inner loop: unconditional float4 loads, 4 columns per thread
//   - atomicAdd partials into out (pre-seeded with br by k_init)
__global__ __launch_bounds__(GEMV_BLOCK) void k_gemv(const float* __restrict__ Wr,
                                                     const float* __restrict__ h,
                                                     float* __restrict__ out) {
  __shared__ float hs[KC];
  __shared__ int ks[KC];
  __shared__ int cnt;
  const int tid = threadIdx.x;
  const int cg = blockIdx.x & 3;    // column group (4 x 1024 cols)
  const int ck = blockIdx.x >> 2;   // k-chunk
  const int k0 = ck * KC;

  if (tid == 0) cnt = 0;
  __syncthreads();
  if (tid < KC) {
    float v = h[k0 + tid];
    if (v != 0.0f) {
      int p = atomicAdd(&cnt, 1);
      hs[p] = v;
      ks[p] = tid;
    }
  }
  __syncthreads();

  const int n = cnt;
  const int col = cg * (GEMV_BLOCK * 4) + tid * 4;
  const float* base = Wr + (size_t)k0 * YDIM + col;
  float ax = 0.f, ay = 0.f, az = 0.f, aw = 0.f;
  for (int q = 0; q < n; ++q) {
    float hv = hs[q];            // broadcast read, conflict-free
    int kk = ks[q];
    const float4 w = *(const float4*)(base + (size_t)kk * YDIM);
    ax += hv * w.x;
    ay += hv * w.y;
    az += hv * w.z;
    aw += hv * w.w;
  }
  atomicAdd(&out[col + 0], ax);
  atomicAdd(&out[col + 1], ay);
  atomicAdd(&out[col + 2], az);
  atomicAdd(&out[col + 3], aw);
}

extern "C" void kernel_launch(void* const* d_in, const int* in_sizes, int n_in,
                              void* d_out, int out_size, void* d_ws, size_t ws_size,
                              hipStream_t stream) {
  const float* x  = (const float*)d_in[0];
  const int*   ei = (const int*)d_in[1];     // int inputs delivered as int32
  const float* W1 = (const float*)d_in[2];
  const float* b1 = (const float*)d_in[3];
  const float* Wr = (const float*)d_in[4];
  const float* br = (const float*)d_in[5];
  float* out = (float*)d_out;

  // Workspace layout (all fp32): deg[4096] dinv[4096] t[4096] h[32768]  = ~180 KB
  float* deg  = (float*)d_ws;
  float* dinv = deg + N_NODES;
  float* t    = dinv + N_NODES;
  float* h    = t + N_NODES;

  k_init   <<<(N_NODES + 255) / 256, 256, 0, stream>>>(deg, t, out, br);
  k_deg    <<<(N_EDGES + 255) / 256, 256, 0, stream>>>(ei, deg);
  k_dinv   <<<(N_NODES + 255) / 256, 256, 0, stream>>>(deg, dinv);
  k_scatter<<<(N_EDGES + 255) / 256, 256, 0, stream>>>(ei, x, dinv, t);
  k_h      <<<(N_NODES + 255) / 256, 256, 0, stream>>>(x, dinv, t, W1, b1, h);
  k_gemv   <<<4 * (K_TOT / KC), GEMV_BLOCK, 0, stream>>>(Wr, h, out);
}